// Round 3
// baseline (532.277 us; speedup 1.0000x reference)
//
#include <hip/hip_runtime.h>
#include <math.h>

#define BB 8
#define NN 4096
#define DD 768
#define EE 8
#define SS 2
#define ES 16
#define FF 3072  // 4*D

// ws layout (floats):
//   xs     [B][ES][D]    98304  @ 0        (zeroed, atomic)
//   ys     [B][ES][D]    98304  @ 98304    (zeroed, atomic)
//   hpre   [E][16][FF]  393216  @ 196608   (zeroed, atomic)
//   logits [B][N][ES]   524288  @ 589824
//   disp   [B][N][ES]   524288  @ 1114112
//   cw     [B][N][ES]   524288  @ 1638400
//   h      [E][16][FF]  393216  @ 2162688
// total 2555904 floats = 10.2 MB

// ---------------------------------------------------------------------------
// K1: logits = x @ phi, + slot-softmax -> disp.
// grid 512 = b(8) x tokgrp(64); block 256 = 4 waves.
// Token-per-lane (64 tokens/block), wave w owns d-quarter [192w,192w+192):
//   x loads: per-lane float4, 64 distinct contiguous lanes (1KB/instr).
//   phi[d][j]: wave-uniform address -> s_load, SGPR operand in v_fma.
// Partial [4][64][16] reduce via padded LDS, softmax on 4-lane shfl groups.
// ---------------------------------------------------------------------------
__global__ __launch_bounds__(256) void k_logits(const float* __restrict__ x,
                                                const float* __restrict__ phi,
                                                float* __restrict__ logits,
                                                float* __restrict__ disp) {
  __shared__ float part[4][64][20];  // pad 16->20 keeps b128 alignment
  const int tid = threadIdx.x;
  const int b   = blockIdx.x >> 6;
  const int n0  = (blockIdx.x & 63) * 64;
  const int w   = __builtin_amdgcn_readfirstlane(tid >> 6);  // d-quarter
  const int l   = tid & 63;                                  // token lane

  const float* xr  = x + (size_t)(b * NN + n0 + l) * DD + 192 * w;
  const float* pr0 = phi + 192 * w * ES;

  float acc[16];
  #pragma unroll
  for (int j = 0; j < 16; ++j) acc[j] = 0.f;

  #pragma unroll 2
  for (int k = 0; k < 48; ++k) {
    const float4 xv = *(const float4*)(xr + 4 * k);
    const float* pr = pr0 + 4 * k * ES;   // uniform -> scalar loads
    #pragma unroll
    for (int j = 0; j < 16; ++j) {
      acc[j] += xv.x * pr[j] + xv.y * pr[ES + j] + xv.z * pr[2 * ES + j] +
                xv.w * pr[3 * ES + j];
    }
  }
  #pragma unroll
  for (int q = 0; q < 4; ++q)
    ((float4*)part[w][l])[q] =
        make_float4(acc[4 * q], acc[4 * q + 1], acc[4 * q + 2], acc[4 * q + 3]);
  __syncthreads();

  // thread (t = tid>>2, jq = tid&3): sum 4 wave-partials, softmax over 16 slots
  const int t  = tid >> 2;
  const int jq = tid & 3;
  float4 s = ((const float4*)part[0][t])[jq];
  #pragma unroll
  for (int ww = 1; ww < 4; ++ww) {
    const float4 p = ((const float4*)part[ww][t])[jq];
    s.x += p.x; s.y += p.y; s.z += p.z; s.w += p.w;
  }
  float m = fmaxf(fmaxf(s.x, s.y), fmaxf(s.z, s.w));
  m = fmaxf(m, __shfl_xor(m, 1));
  m = fmaxf(m, __shfl_xor(m, 2));
  float4 ev = make_float4(__expf(s.x - m), __expf(s.y - m), __expf(s.z - m),
                          __expf(s.w - m));
  float sum = ev.x + ev.y + ev.z + ev.w;
  sum += __shfl_xor(sum, 1);
  sum += __shfl_xor(sum, 2);
  const float inv = 1.f / sum;
  const size_t base = (size_t)(b * NN + n0 + t) * ES + jq * 4;
  *(float4*)(logits + base) = s;
  *(float4*)(disp + base) =
      make_float4(ev.x * inv, ev.y * inv, ev.z * inv, ev.w * inv);
}

// ---------------------------------------------------------------------------
// K2: combine-softmax over tokens -> cw[b,n,es] = exp(l - max_n) / sum_n
// grid 32 = b(8) x jq(4); block 256; thread holds its 16 float4s in regs.
// ---------------------------------------------------------------------------
__global__ __launch_bounds__(256) void k_cstats(const float* __restrict__ logits,
                                                float* __restrict__ cw) {
  const int b  = blockIdx.x >> 2;
  const int jq = blockIdx.x & 3;
  const int tid = threadIdx.x;
  __shared__ float4 red[256];

  float4 vals[16];
  float4 vm = make_float4(-1e30f, -1e30f, -1e30f, -1e30f);
  #pragma unroll
  for (int k = 0; k < 16; ++k) {
    const int n = k * 256 + tid;
    const float4 v = *(const float4*)(&logits[(size_t)(b * NN + n) * ES + jq * 4]);
    vals[k] = v;
    vm.x = fmaxf(vm.x, v.x); vm.y = fmaxf(vm.y, v.y);
    vm.z = fmaxf(vm.z, v.z); vm.w = fmaxf(vm.w, v.w);
  }
  red[tid] = vm;
  __syncthreads();
  for (int s = 128; s > 0; s >>= 1) {
    if (tid < s) {
      float4 a = red[tid], o = red[tid + s];
      a.x = fmaxf(a.x, o.x); a.y = fmaxf(a.y, o.y);
      a.z = fmaxf(a.z, o.z); a.w = fmaxf(a.w, o.w);
      red[tid] = a;
    }
    __syncthreads();
  }
  const float4 gm = red[0];
  __syncthreads();

  float4 sm = make_float4(0.f, 0.f, 0.f, 0.f);
  #pragma unroll
  for (int k = 0; k < 16; ++k) {
    sm.x += __expf(vals[k].x - gm.x); sm.y += __expf(vals[k].y - gm.y);
    sm.z += __expf(vals[k].z - gm.z); sm.w += __expf(vals[k].w - gm.w);
  }
  red[tid] = sm;
  __syncthreads();
  for (int s = 128; s > 0; s >>= 1) {
    if (tid < s) {
      float4 a = red[tid], o = red[tid + s];
      a.x += o.x; a.y += o.y; a.z += o.z; a.w += o.w;
      red[tid] = a;
    }
    __syncthreads();
  }
  const float4 ts = red[0];
  const float4 iv = make_float4(1.f / ts.x, 1.f / ts.y, 1.f / ts.z, 1.f / ts.w);
  #pragma unroll
  for (int k = 0; k < 16; ++k) {
    const int n = k * 256 + tid;
    const float4 c = make_float4(__expf(vals[k].x - gm.x) * iv.x,
                                 __expf(vals[k].y - gm.y) * iv.y,
                                 __expf(vals[k].z - gm.z) * iv.z,
                                 __expf(vals[k].w - gm.w) * iv.w);
    *(float4*)(&cw[(size_t)(b * NN + n) * ES + jq * 4]) = c;
  }
}

// ---------------------------------------------------------------------------
// K3: xs[b,es,d] = sum_n disp[b,n,es] * x[b,n,d]
// grid 512 = b(8) x tokgrp(64); block 192; thread owns float4 at d=4*tid.
// x per-lane float4 (coalesced); disp uniform -> s_load; 16 float4 acc in regs.
// ---------------------------------------------------------------------------
__global__ __launch_bounds__(192) void k_xs(const float* __restrict__ x,
                                            const float* __restrict__ disp,
                                            float* __restrict__ xs) {
  const int b   = blockIdx.x >> 6;
  const int n0  = (blockIdx.x & 63) * 64;
  const int tid = threadIdx.x;

  float4 acc[16];
  #pragma unroll
  for (int e = 0; e < 16; ++e) acc[e] = make_float4(0.f, 0.f, 0.f, 0.f);

  #pragma unroll 2
  for (int t = 0; t < 64; ++t) {
    const size_t tb = (size_t)(b * NN + n0 + t);
    const float4 xv = *(const float4*)(x + tb * DD + 4 * tid);
    const float* dp = disp + tb * ES;   // uniform -> scalar loads
    #pragma unroll
    for (int e = 0; e < 16; ++e) {
      const float wgt = dp[e];
      acc[e].x += wgt * xv.x; acc[e].y += wgt * xv.y;
      acc[e].z += wgt * xv.z; acc[e].w += wgt * xv.w;
    }
  }
  #pragma unroll
  for (int e = 0; e < 16; ++e) {
    float* p = xs + (size_t)(b * ES + e) * DD + 4 * tid;
    atomicAdd(p + 0, acc[e].x); atomicAdd(p + 1, acc[e].y);
    atomicAdd(p + 2, acc[e].z); atomicAdd(p + 3, acc[e].w);
  }
}

// ---------------------------------------------------------------------------
// K4: hpre[e,r,f] += xs_row(r) @ w1[e][d-chunk]   (d-split 8, atomics)
// grid 768 = e(8) x fblk(12) x dpart(8); block 256: f4=tid&63, sg=tid>>6.
// w1 float4 coalesced (1KB/instr, read exactly once); xs rows scalar (SGPR).
// ---------------------------------------------------------------------------
__global__ __launch_bounds__(256) void k_ffn1(const float* __restrict__ xs,
                                              const float* __restrict__ w1,
                                              float* __restrict__ hpre) {
  const int bid  = blockIdx.x;
  const int e    = bid / 96;
  const int fblk = (bid / 8) % 12;
  const int dp   = bid % 8;
  const int tid  = threadIdx.x;
  const int f    = fblk * 256 + 4 * (tid & 63);
  const int sg   = __builtin_amdgcn_readfirstlane(tid >> 6);  // rows 4sg..4sg+3

  const float* xr[4];
  #pragma unroll
  for (int i = 0; i < 4; ++i) {
    const int r = 4 * sg + i;
    xr[i] = xs + (size_t)((r >> 1) * ES + e * SS + (r & 1)) * DD + dp * 96;
  }
  const float* wp = w1 + (size_t)e * DD * FF + (size_t)(dp * 96) * FF + f;

  float4 acc[4];
  #pragma unroll
  for (int i = 0; i < 4; ++i) acc[i] = make_float4(0.f, 0.f, 0.f, 0.f);

  #pragma unroll 4
  for (int dd = 0; dd < 96; ++dd) {
    const float4 wv = *(const float4*)(wp + (size_t)dd * FF);
    #pragma unroll
    for (int i = 0; i < 4; ++i) {
      const float xv = xr[i][dd];   // uniform -> SGPR
      acc[i].x += xv * wv.x; acc[i].y += xv * wv.y;
      acc[i].z += xv * wv.z; acc[i].w += xv * wv.w;
    }
  }
  #pragma unroll
  for (int i = 0; i < 4; ++i) {
    float* p = hpre + (size_t)(e * 16 + 4 * sg + i) * FF + f;
    atomicAdd(p + 0, acc[i].x); atomicAdd(p + 1, acc[i].y);
    atomicAdd(p + 2, acc[i].z); atomicAdd(p + 3, acc[i].w);
  }
}

// ---------------------------------------------------------------------------
// K4b: h = gelu_exact(hpre + b1)   (393216 elems, float4)
// ---------------------------------------------------------------------------
__global__ __launch_bounds__(256) void k_gelu(const float* __restrict__ hpre,
                                              const float* __restrict__ b1,
                                              float* __restrict__ h) {
  const int q4 = blockIdx.x * 256 + threadIdx.x;
  const int q  = 4 * q4;
  const int e  = q / (16 * FF);
  const int f  = q % FF;
  const float4 v  = *(const float4*)(hpre + q);
  const float4 bb = *(const float4*)(b1 + e * FF + f);
  float4 o;
  const float ks = 0.70710678118654752f;
  float a;
  a = v.x + bb.x; o.x = 0.5f * a * (1.f + erff(a * ks));
  a = v.y + bb.y; o.y = 0.5f * a * (1.f + erff(a * ks));
  a = v.z + bb.z; o.z = 0.5f * a * (1.f + erff(a * ks));
  a = v.w + bb.w; o.w = 0.5f * a * (1.f + erff(a * ks));
  *(float4*)(h + q) = o;
}

// ---------------------------------------------------------------------------
// K5: ys[row,d] += h_row @ w2[e][f-chunk]  (+b2 once), f-split 32, atomics
// grid 768 = e(8) x dblk(3) x fp(32); block 256: d4=tid&63, sg=tid>>6.
// w2 float4 coalesced (read exactly once); h rows scalar (SGPR).
// ---------------------------------------------------------------------------
__global__ __launch_bounds__(256) void k_ffn2(const float* __restrict__ h,
                                              const float* __restrict__ w2,
                                              const float* __restrict__ b2,
                                              float* __restrict__ ys) {
  const int bid  = blockIdx.x;
  const int e    = bid / 96;
  const int dblk = (bid / 32) % 3;
  const int fp   = bid % 32;
  const int tid  = threadIdx.x;
  const int dcol = dblk * 256 + 4 * (tid & 63);
  const int sg   = __builtin_amdgcn_readfirstlane(tid >> 6);
  const int f0   = fp * 96;

  const float* hr[4];
  #pragma unroll
  for (int i = 0; i < 4; ++i)
    hr[i] = h + (size_t)(e * 16 + 4 * sg + i) * FF + f0;
  const float* wp = w2 + (size_t)e * FF * DD + (size_t)f0 * DD + dcol;

  float4 acc[4];
  #pragma unroll
  for (int i = 0; i < 4; ++i) acc[i] = make_float4(0.f, 0.f, 0.f, 0.f);
  if (fp == 0) {
    const float4 bv = *(const float4*)(b2 + e * DD + dcol);
    #pragma unroll
    for (int i = 0; i < 4; ++i) acc[i] = bv;
  }

  #pragma unroll 4
  for (int ff = 0; ff < 96; ++ff) {
    const float4 wv = *(const float4*)(wp + (size_t)ff * DD);
    #pragma unroll
    for (int i = 0; i < 4; ++i) {
      const float hv = hr[i][ff];   // uniform -> SGPR
      acc[i].x += hv * wv.x; acc[i].y += hv * wv.y;
      acc[i].z += hv * wv.z; acc[i].w += hv * wv.w;
    }
  }
  #pragma unroll
  for (int i = 0; i < 4; ++i) {
    const int r = 4 * sg + i;
    float* p = ys + (size_t)((r >> 1) * ES + e * SS + (r & 1)) * DD + dcol;
    atomicAdd(p + 0, acc[i].x); atomicAdd(p + 1, acc[i].y);
    atomicAdd(p + 2, acc[i].z); atomicAdd(p + 3, acc[i].w);
  }
}

// ---------------------------------------------------------------------------
// K6: y[b,n,d] = sum_es cw[b,n,es] * ys[b,es,d]
// grid 512 = b(8) x tokgrp(64); block 192; 16 float4 ys rows in regs;
// cw uniform -> s_load; per token: 64 reg-FMA + one float4 store.
// ---------------------------------------------------------------------------
__global__ __launch_bounds__(192) void k_combine(const float* __restrict__ cw,
                                                 const float* __restrict__ ys,
                                                 float* __restrict__ y) {
  const int b   = blockIdx.x >> 6;
  const int n0  = (blockIdx.x & 63) * 64;
  const int tid = threadIdx.x;

  float4 ysr[16];
  #pragma unroll
  for (int es = 0; es < 16; ++es)
    ysr[es] = *(const float4*)(ys + (size_t)(b * ES + es) * DD + 4 * tid);

  #pragma unroll 2
  for (int t = 0; t < 64; ++t) {
    const size_t tb = (size_t)(b * NN + n0 + t);
    const float* cp = cw + tb * ES;   // uniform -> scalar loads
    float4 a = make_float4(0.f, 0.f, 0.f, 0.f);
    #pragma unroll
    for (int es = 0; es < 16; ++es) {
      const float c = cp[es];
      a.x += c * ysr[es].x; a.y += c * ysr[es].y;
      a.z += c * ysr[es].z; a.w += c * ysr[es].w;
    }
    *(float4*)(y + tb * DD + 4 * tid) = a;
  }
}

extern "C" void kernel_launch(void* const* d_in, const int* in_sizes, int n_in,
                              void* d_out, int out_size, void* d_ws, size_t ws_size,
                              hipStream_t stream) {
  const float* x   = (const float*)d_in[0];
  const float* phi = (const float*)d_in[1];
  const float* w1  = (const float*)d_in[2];
  const float* b1  = (const float*)d_in[3];
  const float* w2  = (const float*)d_in[4];
  const float* b2  = (const float*)d_in[5];
  float* y  = (float*)d_out;
  float* ws = (float*)d_ws;

  float* xs     = ws;                // 98304
  float* ys     = ws + 98304;        // 98304
  float* hpre   = ws + 196608;       // 393216
  float* logits = ws + 589824;       // 524288
  float* disp   = ws + 1114112;      // 524288
  float* cwb    = ws + 1638400;      // 524288
  float* h      = ws + 2162688;      // 393216

  // zero the atomic-accumulated region (xs|ys|hpre contiguous)
  hipMemsetAsync(ws, 0, (size_t)589824 * sizeof(float), stream);

  hipLaunchKernelGGL(k_logits,  dim3(512), dim3(256), 0, stream, x, phi, logits, disp);
  hipLaunchKernelGGL(k_cstats,  dim3(32),  dim3(256), 0, stream, logits, cwb);
  hipLaunchKernelGGL(k_xs,      dim3(512), dim3(192), 0, stream, x, disp, xs);
  hipLaunchKernelGGL(k_ffn1,    dim3(768), dim3(256), 0, stream, xs, w1, hpre);
  hipLaunchKernelGGL(k_gelu,    dim3(384), dim3(256), 0, stream, hpre, b1, h);
  hipLaunchKernelGGL(k_ffn2,    dim3(768), dim3(256), 0, stream, h, w2, b2, ys);
  hipLaunchKernelGGL(k_combine, dim3(512), dim3(192), 0, stream, cwb, ys, y);
}

// Round 4
// 383.029 us; speedup vs baseline: 1.3897x; 1.3897x over previous
//
#include <hip/hip_runtime.h>
#include <math.h>

#define BB 8
#define NN 4096
#define DD 768
#define EE 8
#define SS 2
#define ES 16
#define FF 3072  // 4*D

// ws layout (floats) — NO atomics anywhere, so no zero-init needed:
//   A      @ 0        6291456  xspart[8][64][16][768]; reused later as
//                              hpart[8][128][3072] then yspart[32][128][768]
//   logits @ 6291456  524288
//   disp   @ 6815744  524288
//   xs     @ 7340032  98304
//   h      @ 7438336  393216
//   ys     @ 7831552  98304
//   mpart  @ 7929856  4096    [8][32][16]
//   spart  @ 7933952  4096    [8][32][16]
//   cmax   @ 7938048  128
//   cinv   @ 7938176  128
// total 7938304 floats = 31.8 MB

// ---------------------------------------------------------------------------
// K1: logits = x @ phi, + slot-softmax -> disp.   (unchanged from round 3)
// grid 512 = b(8) x tokgrp(64); block 256 = 4 waves; token-per-lane,
// wave owns d-quarter; x per-lane float4; phi wave-uniform -> s_load.
// ---------------------------------------------------------------------------
__global__ __launch_bounds__(256) void k_logits(const float* __restrict__ x,
                                                const float* __restrict__ phi,
                                                float* __restrict__ logits,
                                                float* __restrict__ disp) {
  __shared__ float part[4][64][20];
  const int tid = threadIdx.x;
  const int b   = blockIdx.x >> 6;
  const int n0  = (blockIdx.x & 63) * 64;
  const int w   = __builtin_amdgcn_readfirstlane(tid >> 6);
  const int l   = tid & 63;

  const float* xr  = x + (size_t)(b * NN + n0 + l) * DD + 192 * w;
  const float* pr0 = phi + 192 * w * ES;

  float acc[16];
  #pragma unroll
  for (int j = 0; j < 16; ++j) acc[j] = 0.f;

  #pragma unroll 2
  for (int k = 0; k < 48; ++k) {
    const float4 xv = *(const float4*)(xr + 4 * k);
    const float* pr = pr0 + 4 * k * ES;   // uniform -> scalar loads
    #pragma unroll
    for (int j = 0; j < 16; ++j) {
      acc[j] += xv.x * pr[j] + xv.y * pr[ES + j] + xv.z * pr[2 * ES + j] +
                xv.w * pr[3 * ES + j];
    }
  }
  #pragma unroll
  for (int q = 0; q < 4; ++q)
    ((float4*)part[w][l])[q] =
        make_float4(acc[4 * q], acc[4 * q + 1], acc[4 * q + 2], acc[4 * q + 3]);
  __syncthreads();

  const int t  = tid >> 2;
  const int jq = tid & 3;
  float4 s = ((const float4*)part[0][t])[jq];
  #pragma unroll
  for (int ww = 1; ww < 4; ++ww) {
    const float4 p = ((const float4*)part[ww][t])[jq];
    s.x += p.x; s.y += p.y; s.z += p.z; s.w += p.w;
  }
  float m = fmaxf(fmaxf(s.x, s.y), fmaxf(s.z, s.w));
  m = fmaxf(m, __shfl_xor(m, 1));
  m = fmaxf(m, __shfl_xor(m, 2));
  float4 ev = make_float4(__expf(s.x - m), __expf(s.y - m), __expf(s.z - m),
                          __expf(s.w - m));
  float sum = ev.x + ev.y + ev.z + ev.w;
  sum += __shfl_xor(sum, 1);
  sum += __shfl_xor(sum, 2);
  const float inv = 1.f / sum;
  const size_t base = (size_t)(b * NN + n0 + t) * ES + jq * 4;
  *(float4*)(logits + base) = s;
  *(float4*)(disp + base) =
      make_float4(ev.x * inv, ev.y * inv, ev.z * inv, ev.w * inv);
}

// ---------------------------------------------------------------------------
// K2a: per-chunk combine-softmax partials: mpart/spart[b][ch][16]
// grid 256 = b(8) x chunk(32, 128 tokens); block 128; LDS tree-reduce.
// ---------------------------------------------------------------------------
__global__ __launch_bounds__(128) void k_cpart(const float* __restrict__ logits,
                                               float* __restrict__ mpart,
                                               float* __restrict__ spart) {
  __shared__ float4 red[128][4];
  const int b   = blockIdx.x >> 5;
  const int ch  = blockIdx.x & 31;
  const int tid = threadIdx.x;
  const size_t base = (size_t)(b * NN + ch * 128 + tid) * ES;

  float4 v[4];
  #pragma unroll
  for (int q = 0; q < 4; ++q) v[q] = *(const float4*)(logits + base + 4 * q);
  #pragma unroll
  for (int q = 0; q < 4; ++q) red[tid][q] = v[q];
  __syncthreads();
  for (int s = 64; s > 0; s >>= 1) {
    if (tid < s) {
      #pragma unroll
      for (int q = 0; q < 4; ++q) {
        float4 a = red[tid][q], o = red[tid + s][q];
        a.x = fmaxf(a.x, o.x); a.y = fmaxf(a.y, o.y);
        a.z = fmaxf(a.z, o.z); a.w = fmaxf(a.w, o.w);
        red[tid][q] = a;
      }
    }
    __syncthreads();
  }
  float4 mx[4];
  #pragma unroll
  for (int q = 0; q < 4; ++q) mx[q] = red[0][q];
  __syncthreads();

  #pragma unroll
  for (int q = 0; q < 4; ++q)
    red[tid][q] = make_float4(__expf(v[q].x - mx[q].x), __expf(v[q].y - mx[q].y),
                              __expf(v[q].z - mx[q].z), __expf(v[q].w - mx[q].w));
  __syncthreads();
  for (int s = 64; s > 0; s >>= 1) {
    if (tid < s) {
      #pragma unroll
      for (int q = 0; q < 4; ++q) {
        float4 a = red[tid][q], o = red[tid + s][q];
        a.x += o.x; a.y += o.y; a.z += o.z; a.w += o.w;
        red[tid][q] = a;
      }
    }
    __syncthreads();
  }
  if (tid == 0) {
    const int ob = (b * 32 + ch) * ES;
    #pragma unroll
    for (int q = 0; q < 4; ++q) {
      *(float4*)(mpart + ob + 4 * q) = mx[q];
      *(float4*)(spart + ob + 4 * q) = red[0][q];
    }
  }
}

// ---------------------------------------------------------------------------
// K2b: global combine stats: cmax[b][16], cinv[b][16] = 1/sum (rescaled)
// grid 8; block 64 (16 active lanes). Tiny.
// ---------------------------------------------------------------------------
__global__ __launch_bounds__(64) void k_cfin(const float* __restrict__ mpart,
                                             const float* __restrict__ spart,
                                             float* __restrict__ cmax,
                                             float* __restrict__ cinv) {
  const int b = blockIdx.x;
  const int j = threadIdx.x;
  if (j < 16) {
    float m = -1e30f;
    #pragma unroll 4
    for (int c = 0; c < 32; ++c)
      m = fmaxf(m, mpart[(b * 32 + c) * ES + j]);
    float S = 0.f;
    #pragma unroll 4
    for (int c = 0; c < 32; ++c)
      S += spart[(b * 32 + c) * ES + j] * __expf(mpart[(b * 32 + c) * ES + j] - m);
    cmax[b * ES + j] = m;
    cinv[b * ES + j] = 1.f / S;
  }
}

// ---------------------------------------------------------------------------
// K3a: xspart[b][p][es][d] = sum over 64 tokens of disp*x  (plain stores)
// grid 512 = b(8) x part(64); block 192; thread owns float4 at d=4*tid.
// ---------------------------------------------------------------------------
__global__ __launch_bounds__(192) void k_xsA(const float* __restrict__ x,
                                             const float* __restrict__ disp,
                                             float* __restrict__ xspart) {
  const int b   = blockIdx.x >> 6;
  const int n0  = (blockIdx.x & 63) * 64;
  const int tid = threadIdx.x;

  float4 acc[16];
  #pragma unroll
  for (int e = 0; e < 16; ++e) acc[e] = make_float4(0.f, 0.f, 0.f, 0.f);

  #pragma unroll 4
  for (int t = 0; t < 64; ++t) {
    const size_t tb = (size_t)(b * NN + n0 + t);
    const float4 xv = *(const float4*)(x + tb * DD + 4 * tid);
    const float* dp = disp + tb * ES;   // uniform -> scalar loads
    #pragma unroll
    for (int e = 0; e < 16; ++e) {
      const float wgt = dp[e];
      acc[e].x += wgt * xv.x; acc[e].y += wgt * xv.y;
      acc[e].z += wgt * xv.z; acc[e].w += wgt * xv.w;
    }
  }
  #pragma unroll
  for (int e = 0; e < 16; ++e)
    *(float4*)(xspart + ((size_t)blockIdx.x * 16 + e) * DD + 4 * tid) = acc[e];
}

// ---------------------------------------------------------------------------
// K3b: xs[b][es][d] = sum_p xspart[b][p][es][d]   (24 MB, L2/L3-hot)
// grid 96 x 256; one float4 per thread, 64 strided partial loads.
// ---------------------------------------------------------------------------
__global__ __launch_bounds__(256) void k_xsB(const float* __restrict__ xspart,
                                             float* __restrict__ xs) {
  const int q4  = blockIdx.x * 256 + threadIdx.x;  // [0, 24576)
  const int row = q4 / 192;                        // b*16+es
  const int c4  = q4 % 192;
  const int b   = row >> 4;
  const int e   = row & 15;
  float4 s = make_float4(0.f, 0.f, 0.f, 0.f);
  #pragma unroll 8
  for (int p = 0; p < 64; ++p) {
    const float4 v =
        *(const float4*)(xspart + (((size_t)(b * 64 + p)) * 16 + e) * DD + 4 * c4);
    s.x += v.x; s.y += v.y; s.z += v.z; s.w += v.w;
  }
  *(float4*)(xs + (size_t)row * DD + 4 * c4) = s;
}

// ---------------------------------------------------------------------------
// K4: hpart[dp][e*16+r][f] = xs_row(r) @ w1[e][d-chunk]   (plain stores)
// grid 768 = e(8) x fblk(12) x dp(8); block 256: f4=tid&63, sg=tid>>6.
// ---------------------------------------------------------------------------
__global__ __launch_bounds__(256) void k_ffn1(const float* __restrict__ xs,
                                              const float* __restrict__ w1,
                                              float* __restrict__ hpart) {
  const int bid  = blockIdx.x;
  const int e    = bid / 96;
  const int fblk = (bid / 8) % 12;
  const int dp   = bid % 8;
  const int tid  = threadIdx.x;
  const int f    = fblk * 256 + 4 * (tid & 63);
  const int sg   = __builtin_amdgcn_readfirstlane(tid >> 6);

  const float* xr[4];
  #pragma unroll
  for (int i = 0; i < 4; ++i) {
    const int r = 4 * sg + i;
    xr[i] = xs + (size_t)((r >> 1) * ES + e * SS + (r & 1)) * DD + dp * 96;
  }
  const float* wp = w1 + (size_t)e * DD * FF + (size_t)(dp * 96) * FF + f;

  float4 acc[4];
  #pragma unroll
  for (int i = 0; i < 4; ++i) acc[i] = make_float4(0.f, 0.f, 0.f, 0.f);

  #pragma unroll 4
  for (int dd = 0; dd < 96; ++dd) {
    const float4 wv = *(const float4*)(wp + (size_t)dd * FF);
    #pragma unroll
    for (int i = 0; i < 4; ++i) {
      const float xv = xr[i][dd];   // uniform -> SGPR
      acc[i].x += xv * wv.x; acc[i].y += xv * wv.y;
      acc[i].z += xv * wv.z; acc[i].w += xv * wv.w;
    }
  }
  #pragma unroll
  for (int i = 0; i < 4; ++i)
    *(float4*)(hpart + ((size_t)dp * 128 + e * 16 + 4 * sg + i) * FF + f) = acc[i];
}

// ---------------------------------------------------------------------------
// K4b: h = gelu_exact(sum_dp hpart + b1)   (reduce 8 partials + activation)
// grid 384 x 256; one float4 per thread.
// ---------------------------------------------------------------------------
__global__ __launch_bounds__(256) void k_gelu(const float* __restrict__ hpart,
                                              const float* __restrict__ b1,
                                              float* __restrict__ h) {
  const int q4  = blockIdx.x * 256 + threadIdx.x;  // [0, 98304)
  const int row = q4 / 768;                        // e*16+r
  const int c4  = q4 % 768;
  const int e   = row >> 4;
  float4 s = make_float4(0.f, 0.f, 0.f, 0.f);
  #pragma unroll
  for (int dp = 0; dp < 8; ++dp) {
    const float4 v = *(const float4*)(hpart + ((size_t)dp * 128 + row) * FF + 4 * c4);
    s.x += v.x; s.y += v.y; s.z += v.z; s.w += v.w;
  }
  const float4 bb = *(const float4*)(b1 + e * FF + 4 * c4);
  const float ks = 0.70710678118654752f;
  float a;
  float4 o;
  a = s.x + bb.x; o.x = 0.5f * a * (1.f + erff(a * ks));
  a = s.y + bb.y; o.y = 0.5f * a * (1.f + erff(a * ks));
  a = s.z + bb.z; o.z = 0.5f * a * (1.f + erff(a * ks));
  a = s.w + bb.w; o.w = 0.5f * a * (1.f + erff(a * ks));
  *(float4*)(h + (size_t)row * FF + 4 * c4) = o;
}

// ---------------------------------------------------------------------------
// K5: yspart[fp][e*16+r][d] = h_row(r) @ w2[e][f-chunk]   (plain stores)
// grid 768 = e(8) x dblk(3) x fp(32); block 256: d4=tid&63, sg=tid>>6.
// ---------------------------------------------------------------------------
__global__ __launch_bounds__(256) void k_ffn2(const float* __restrict__ h,
                                              const float* __restrict__ w2,
                                              float* __restrict__ yspart) {
  const int bid  = blockIdx.x;
  const int e    = bid / 96;
  const int dblk = (bid / 32) % 3;
  const int fp   = bid % 32;
  const int tid  = threadIdx.x;
  const int dcol = dblk * 256 + 4 * (tid & 63);
  const int sg   = __builtin_amdgcn_readfirstlane(tid >> 6);
  const int f0   = fp * 96;

  const float* hr[4];
  #pragma unroll
  for (int i = 0; i < 4; ++i)
    hr[i] = h + (size_t)(e * 16 + 4 * sg + i) * FF + f0;
  const float* wp = w2 + (size_t)e * FF * DD + (size_t)f0 * DD + dcol;

  float4 acc[4];
  #pragma unroll
  for (int i = 0; i < 4; ++i) acc[i] = make_float4(0.f, 0.f, 0.f, 0.f);

  #pragma unroll 4
  for (int ff = 0; ff < 96; ++ff) {
    const float4 wv = *(const float4*)(wp + (size_t)ff * DD);
    #pragma unroll
    for (int i = 0; i < 4; ++i) {
      const float hv = hr[i][ff];   // uniform -> SGPR
      acc[i].x += hv * wv.x; acc[i].y += hv * wv.y;
      acc[i].z += hv * wv.z; acc[i].w += hv * wv.w;
    }
  }
  #pragma unroll
  for (int i = 0; i < 4; ++i)
    *(float4*)(yspart + ((size_t)fp * 128 + e * 16 + 4 * sg + i) * DD + dcol) = acc[i];
}

// ---------------------------------------------------------------------------
// K5b: ys[b][es][d] = sum_fp yspart[fp][e*16 + b*2+s][d] + b2[e][d]
// grid 96 x 256; one float4 per thread, 32 strided partial loads.
// ---------------------------------------------------------------------------
__global__ __launch_bounds__(256) void k_ysred(const float* __restrict__ yspart,
                                               const float* __restrict__ b2,
                                               float* __restrict__ ys) {
  const int q4  = blockIdx.x * 256 + threadIdx.x;  // [0, 24576)
  const int q   = q4 / 192;                        // b*16+es
  const int c4  = q4 % 192;
  const int b   = q >> 4;
  const int es  = q & 15;
  const int e   = es >> 1;
  const int s   = es & 1;
  const int prow = e * 16 + b * 2 + s;
  float4 acc = *(const float4*)(b2 + e * DD + 4 * c4);
  #pragma unroll 8
  for (int fp = 0; fp < 32; ++fp) {
    const float4 v = *(const float4*)(yspart + ((size_t)fp * 128 + prow) * DD + 4 * c4);
    acc.x += v.x; acc.y += v.y; acc.z += v.z; acc.w += v.w;
  }
  *(float4*)(ys + (size_t)q * DD + 4 * c4) = acc;
}

// ---------------------------------------------------------------------------
// K6: y[b,n,d] = sum_es exp(logits-cmax)*cinv * ys[b,es,d]
// grid 512 = b(8) x tokgrp(64); block 192; 16 float4 ys rows in regs;
// logits uniform -> s_load; exp computed inline (cw buffer eliminated).
// ---------------------------------------------------------------------------
__global__ __launch_bounds__(192) void k_combine(const float* __restrict__ logits,
                                                 const float* __restrict__ ys,
                                                 const float* __restrict__ cmax,
                                                 const float* __restrict__ cinv,
                                                 float* __restrict__ y) {
  const int b   = blockIdx.x >> 6;
  const int n0  = (blockIdx.x & 63) * 64;
  const int tid = threadIdx.x;

  float4 ysr[16];
  float cm[16], ci[16];
  #pragma unroll
  for (int es = 0; es < 16; ++es) {
    cm[es] = cmax[b * ES + es];   // uniform -> SGPR
    ci[es] = cinv[b * ES + es];
    ysr[es] = *(const float4*)(ys + (size_t)(b * ES + es) * DD + 4 * tid);
  }
  #pragma unroll 2
  for (int t = 0; t < 64; ++t) {
    const size_t tb = (size_t)(b * NN + n0 + t);
    const float* lp = logits + tb * ES;   // uniform -> scalar loads
    float4 a = make_float4(0.f, 0.f, 0.f, 0.f);
    #pragma unroll
    for (int es = 0; es < 16; ++es) {
      const float c = __expf(lp[es] - cm[es]) * ci[es];
      a.x += c * ysr[es].x; a.y += c * ysr[es].y;
      a.z += c * ysr[es].z; a.w += c * ysr[es].w;
    }
    *(float4*)(y + tb * DD + 4 * tid) = a;
  }
}

extern "C" void kernel_launch(void* const* d_in, const int* in_sizes, int n_in,
                              void* d_out, int out_size, void* d_ws, size_t ws_size,
                              hipStream_t stream) {
  const float* x   = (const float*)d_in[0];
  const float* phi = (const float*)d_in[1];
  const float* w1  = (const float*)d_in[2];
  const float* b1  = (const float*)d_in[3];
  const float* w2  = (const float*)d_in[4];
  const float* b2  = (const float*)d_in[5];
  float* y  = (float*)d_out;
  float* ws = (float*)d_ws;

  float* A      = ws;                // 6291456: xspart / hpart / yspart (reused)
  float* logits = ws + 6291456;      // 524288
  float* disp   = ws + 6815744;      // 524288
  float* xs     = ws + 7340032;      // 98304
  float* h      = ws + 7438336;      // 393216
  float* ys     = ws + 7831552;      // 98304
  float* mpart  = ws + 7929856;      // 4096
  float* spart  = ws + 7933952;      // 4096
  float* cmax   = ws + 7938048;      // 128
  float* cinv   = ws + 7938176;      // 128

  hipLaunchKernelGGL(k_logits,  dim3(512), dim3(256), 0, stream, x, phi, logits, disp);
  hipLaunchKernelGGL(k_cpart,   dim3(256), dim3(128), 0, stream, logits, mpart, spart);
  hipLaunchKernelGGL(k_cfin,    dim3(8),   dim3(64),  0, stream, mpart, spart, cmax, cinv);
  hipLaunchKernelGGL(k_xsA,     dim3(512), dim3(192), 0, stream, x, disp, A);
  hipLaunchKernelGGL(k_xsB,     dim3(96),  dim3(256), 0, stream, A, xs);
  hipLaunchKernelGGL(k_ffn1,    dim3(768), dim3(256), 0, stream, xs, w1, A);
  hipLaunchKernelGGL(k_gelu,    dim3(384), dim3(256), 0, stream, A, b1, h);
  hipLaunchKernelGGL(k_ffn2,    dim3(768), dim3(256), 0, stream, h, w2, A);
  hipLaunchKernelGGL(k_ysred,   dim3(96),  dim3(256), 0, stream, A, b2, ys);
  hipLaunchKernelGGL(k_combine, dim3(512), dim3(192), 0, stream, logits, ys, cmax, cinv, y);
}